// Round 4
// baseline (90.785 us; speedup 1.0000x reference)
//
#include <hip/hip_runtime.h>
#include <hip/hip_cooperative_groups.h>
#include <stdint.h>

namespace cg = cooperative_groups;

// FSUConv2d single-cycle bipolar forward == binary XNOR-conv with threshold:
//   per tap popc(x&w) + popc(~x&~w) = 64 - popc(x^w); zero-padded xpack makes
//   pad taps follow the same formula. pc = 576 - S + b_bit, S = sum popc(x^w).
//   out = (pc >= 577) = (S == 0 && b_bit) = (all 9 tap words EQUAL && b_bit).
// Single cooperative dispatch: phase1 pack -> grid.sync -> phase2 conv.

#define NB   16
#define CIN  64
#define HH   56
#define WWD  56
#define COUT 64
#define HW   (HH * WWD)            // 3136
#define PSTRIDE 64                 // padded row stride (words)
#define PROWS   58
#define PWORDS  (PROWS * PSTRIDE)  // 3712 words per image
#define NPACK (8 * NB * HW)        // 401408 pack items (8 ch per item)
#define NPAD  (NB * 228)           // 3648 pad-word zeroing items
#define NWPK  (COUT * 9)           // 576 weight-pack items
#define K1TOT (NPACK + NPAD + NWPK)
#define NCONV (NB * COUT * HW / 8) // 401408 conv items (8 outputs each)
#define NBLK  1024
#define GRIDTH (NBLK * 256)

__device__ __forceinline__ void pack_item(int tid, const float* __restrict__ x,
                                          const float* __restrict__ w,
                                          uint64_t* __restrict__ xpack,
                                          uint64_t* __restrict__ wpack) {
    if (tid < NPACK) {
        int pos = tid % (NB * HW);
        int cg8 = tid / (NB * HW);
        int n   = pos / HW;
        int hw  = pos - n * HW;
        int h   = hw / WWD;
        int ww  = hw - h * WWD;
        const float* xp = x + (size_t)n * CIN * HW + (size_t)(cg8 * 8) * HW + hw;
        uint32_t b = 0;
#pragma unroll
        for (int i = 0; i < 8; ++i) b |= (uint32_t)(xp[(size_t)i * HW] != 0.0f) << i;
        size_t word = (size_t)n * PWORDS + (size_t)(h + 1) * PSTRIDE + (ww + 1);
        ((uint8_t*)xpack)[word * 8 + cg8] = (uint8_t)b;
    } else if (tid < NPACK + NPAD) {
        // pad words conv reads: row 0 cols 0..57, row 57 cols 0..57,
        // rows 1..56 cols {0,57}.  228 per image.
        int idx = tid - NPACK;
        int n = idx / 228;
        int r = idx - n * 228;
        int row, col;
        if (r < 58)       { row = 0;  col = r; }
        else if (r < 116) { row = 57; col = r - 58; }
        else { int rr = r - 116; row = 1 + (rr >> 1); col = (rr & 1) ? 57 : 0; }
        xpack[(size_t)n * PWORDS + row * PSTRIDE + col] = 0ull;
    } else if (tid < K1TOT) {
        int idx = tid - (NPACK + NPAD);
        int co = idx / 9, j = idx - co * 9;
        uint64_t bits = 0;
#pragma unroll
        for (int c = 0; c < CIN; ++c)
            bits |= (uint64_t)(w[(size_t)co * CIN * 9 + c * 9 + j] > 0.0f) << c;
        wpack[idx] = bits;
    }
}

__device__ __forceinline__ void conv_item(int tid, const uint64_t* __restrict__ xpack,
                                          const uint64_t* __restrict__ wsh,
                                          const float* __restrict__ bsh,
                                          float* __restrict__ out) {
    int q     = tid % 392;                      // hp*14 + wg
    int plane = tid / 392;                      // n*64 + co
    int co = plane & 63;
    int n  = plane >> 6;
    int hp = q / 14;
    int wg = q - hp * 14;
    int h0 = hp * 2, w0 = wg * 4;

    const uint64_t* P = xpack + (size_t)n * PWORDS + (size_t)h0 * PSTRIDE + w0;
    uint64_t r[4][6];
#pragma unroll
    for (int rr = 0; rr < 4; ++rr) {
        const ulonglong2* p = (const ulonglong2*)(P + rr * PSTRIDE);
        ulonglong2 a = p[0], b = p[1], c = p[2];
        r[rr][0] = a.x; r[rr][1] = a.y; r[rr][2] = b.x;
        r[rr][3] = b.y; r[rr][4] = c.x; r[rr][5] = c.y;
    }
    uint64_t wp[9];
#pragma unroll
    for (int t = 0; t < 9; ++t) wp[t] = wsh[co * 9 + t];
    int bb = bsh[co] > 0.0f;

    float res[8];
#pragma unroll
    for (int orow = 0; orow < 2; ++orow) {
#pragma unroll
        for (int o = 0; o < 4; ++o) {
            int e = bb;
#pragma unroll
            for (int kh = 0; kh < 3; ++kh)
#pragma unroll
                for (int kw = 0; kw < 3; ++kw)
                    e &= (r[orow + kh][o + kw] == wp[kh * 3 + kw]);
            res[orow * 4 + o] = e ? 1.0f : 0.0f;
        }
    }
    float* ob = out + (size_t)plane * HW + (size_t)h0 * WWD + w0;
    *(float4*)ob         = *(const float4*)&res[0];
    *(float4*)(ob + WWD) = *(const float4*)&res[4];
}

// ---- fused cooperative kernel: pack -> grid.sync -> conv ----
__global__ __launch_bounds__(256, 4) void fused_kernel(const float* __restrict__ x,
                                                       const float* __restrict__ w,
                                                       const float* __restrict__ bias,
                                                       uint64_t* __restrict__ xpack,
                                                       uint64_t* __restrict__ wpack,
                                                       float* __restrict__ out) {
    int tid0 = blockIdx.x * 256 + threadIdx.x;
    for (int tid = tid0; tid < K1TOT; tid += GRIDTH)
        pack_item(tid, x, w, xpack, wpack);

    cg::this_grid().sync();

    __shared__ uint64_t wsh[COUT * 9];
    __shared__ float bsh[COUT];
    for (int i = threadIdx.x; i < COUT * 9; i += 256) wsh[i] = wpack[i];
    if (threadIdx.x < COUT) bsh[threadIdx.x] = bias[threadIdx.x];
    __syncthreads();

    for (int tid = tid0; tid < NCONV; tid += GRIDTH)
        conv_item(tid, xpack, wsh, bsh, out);
}

// ---- fallback (2 separate dispatches), identical math ----
__global__ __launch_bounds__(256) void prep_pack_kernel(const float* __restrict__ x,
                                                        const float* __restrict__ w,
                                                        uint64_t* __restrict__ xpack,
                                                        uint64_t* __restrict__ wpack) {
    int tid = blockIdx.x * 256 + threadIdx.x;
    if (tid < K1TOT) pack_item(tid, x, w, xpack, wpack);
}

__global__ __launch_bounds__(256) void conv_kernel(const uint64_t* __restrict__ xpack,
                                                   const uint64_t* __restrict__ wpack,
                                                   const float* __restrict__ bias,
                                                   float* __restrict__ out) {
    __shared__ uint64_t wsh[COUT * 9];
    __shared__ float bsh[COUT];
    for (int i = threadIdx.x; i < COUT * 9; i += 256) wsh[i] = wpack[i];
    if (threadIdx.x < COUT) bsh[threadIdx.x] = bias[threadIdx.x];
    __syncthreads();
    int tid = blockIdx.x * 256 + threadIdx.x;
    if (tid < NCONV) conv_item(tid, xpack, wsh, bsh, out);
}

extern "C" void kernel_launch(void* const* d_in, const int* in_sizes, int n_in,
                              void* d_out, int out_size, void* d_ws, size_t ws_size,
                              hipStream_t stream) {
    const float* x    = (const float*)d_in[0];
    const float* wgt  = (const float*)d_in[1];
    const float* bias = (const float*)d_in[2];
    float* out = (float*)d_out;

    // workspace: [0, 4608) wpack ; [8192, 8192 + 475136) xpack (padded)
    uint64_t* wpack = (uint64_t*)d_ws;
    uint64_t* xpack = (uint64_t*)((char*)d_ws + 8192);

    void* args[] = {(void*)&x, (void*)&wgt, (void*)&bias,
                    (void*)&xpack, (void*)&wpack, (void*)&out};
    hipError_t e = hipLaunchCooperativeKernel((const void*)fused_kernel,
                                              dim3(NBLK), dim3(256), args, 0, stream);
    if (e != hipSuccess) {
        // fallback: two plain dispatches (R3 structure)
        prep_pack_kernel<<<(K1TOT + 255) / 256, 256, 0, stream>>>(x, wgt, xpack, wpack);
        conv_kernel<<<(NCONV + 255) / 256, 256, 0, stream>>>(xpack, wpack, bias, out);
    }
}

// Round 5
// 26.258 us; speedup vs baseline: 3.4574x; 3.4574x over previous
//
#include <hip/hip_runtime.h>
#include <stdint.h>

// FSUConv2d single-cycle bipolar forward == binary XNOR-conv with threshold:
//   per tap popc(x&w) + popc(~x&~w) = 64 - popc(x^w); zero-padded tile makes
//   pad taps follow the same formula. pc = 576 - S + b_bit, S = sum popc(x^w).
//   out = (pc >= 577) = (S == 0 && b_bit) = (all 9 tap words EQUAL && b_bit).
//
// Single plain dispatch, NO grid sync (R4 showed cg::grid.sync costs ~80us on
// 8-XCD MI355X). Each block is self-sufficient: packs its own 4-row x-halo
// (2x read redundancy) + the L2-resident weights into LDS, one __syncthreads,
// then equality-conv for all 64 couts over its 2x56 output band.

#define NB   16
#define CIN  64
#define HH   56
#define WWD  56
#define COUT 64
#define HW   (HH * WWD)             // 3136
#define RPB  2                      // output rows per block
#define BANDS (HH / RPB)            // 28
#define NBLOCKS (NB * BANDS)        // 448
#define XT_ROWS (RPB + 2)           // 4 padded input rows
#define XT_COLS 58                  // 56 + 2 pad cols
#define XT_WORDS (XT_ROWS * XT_COLS)  // 232

__global__ __launch_bounds__(256) void fused_conv(const float* __restrict__ x,
                                                  const float* __restrict__ w,
                                                  const float* __restrict__ bias,
                                                  float* __restrict__ out) {
    __shared__ uint64_t xt[XT_WORDS];     // 1856 B padded bit tile
    __shared__ uint64_t wsh[COUT * 9];    // 4608 B weight words
    __shared__ int bflag[COUT];

    int n    = blockIdx.x / BANDS;
    int band = blockIdx.x % BANDS;
    int h0   = band * RPB;

    // ---- phase 1a: pack x halo (rows h0-1 .. h0+RPB) into padded LDS tile
    {
        int t = threadIdx.x;
        if (t < XT_WORDS) {
            int rr = t / XT_COLS;
            int c  = t % XT_COLS;
            int gh = h0 - 1 + rr;
            uint64_t bits = 0;
            if (c >= 1 && c <= WWD && gh >= 0 && gh < HH) {
                const float* xp = x + (size_t)n * CIN * HW + (size_t)gh * WWD + (c - 1);
#pragma unroll
                for (int ch = 0; ch < CIN; ++ch)
                    bits |= (uint64_t)(xp[(size_t)ch * HW] != 0.0f) << ch;
            }
            xt[t] = bits;
        }
    }
    // ---- phase 1b: pack weight words (w is L2-resident: 147 KB, read by all)
    for (int i = threadIdx.x; i < COUT * 9; i += 256) {
        int co = i / 9, j = i - co * 9;
        const float* wp = w + (size_t)co * CIN * 9 + j;
        uint64_t bits = 0;
#pragma unroll
        for (int ch = 0; ch < CIN; ++ch)
            bits |= (uint64_t)(wp[ch * 9] > 0.0f) << ch;
        wsh[i] = bits;
    }
    if (threadIdx.x < COUT) bflag[threadIdx.x] = bias[threadIdx.x] > 0.0f;
    __syncthreads();

    // ---- phase 2: equality-conv; 896 items of (2 rows x 4 cols) x 64 couts
    for (int item = threadIdx.x; item < COUT * 14; item += 256) {
        int co   = item / 14;
        int quad = item - co * 14;
        int c0   = quad * 4;

        uint64_t r[XT_ROWS][6];
#pragma unroll
        for (int rr = 0; rr < XT_ROWS; ++rr) {
            const ulonglong2* p = (const ulonglong2*)&xt[rr * XT_COLS + c0];  // 16B aligned
            ulonglong2 a = p[0], b = p[1], cc = p[2];
            r[rr][0] = a.x; r[rr][1] = a.y; r[rr][2] = b.x;
            r[rr][3] = b.y; r[rr][4] = cc.x; r[rr][5] = cc.y;
        }
        uint64_t wp[9];
#pragma unroll
        for (int k = 0; k < 9; ++k) wp[k] = wsh[co * 9 + k];
        int bb = bflag[co];

        float4 res[RPB];
#pragma unroll
        for (int orow = 0; orow < RPB; ++orow) {
            float v[4];
#pragma unroll
            for (int o = 0; o < 4; ++o) {
                int e = bb;
#pragma unroll
                for (int kh = 0; kh < 3; ++kh)
#pragma unroll
                    for (int kw = 0; kw < 3; ++kw)
                        e &= (r[orow + kh][o + kw] == wp[kh * 3 + kw]);
                v[o] = e ? 1.0f : 0.0f;
            }
            res[orow] = make_float4(v[0], v[1], v[2], v[3]);
        }
        float* ob = out + ((size_t)n * COUT + co) * HW + (size_t)h0 * WWD + c0;
        *(float4*)ob         = res[0];
        *(float4*)(ob + WWD) = res[1];
    }
}

extern "C" void kernel_launch(void* const* d_in, const int* in_sizes, int n_in,
                              void* d_out, int out_size, void* d_ws, size_t ws_size,
                              hipStream_t stream) {
    const float* x    = (const float*)d_in[0];
    const float* wgt  = (const float*)d_in[1];
    const float* bias = (const float*)d_in[2];
    float* out = (float*)d_out;

    fused_conv<<<NBLOCKS, 256, 0, stream>>>(x, wgt, bias, out);
}

// Round 6
// 20.200 us; speedup vs baseline: 4.4944x; 1.2999x over previous
//
#include <hip/hip_runtime.h>
#include <stdint.h>

// FSUConv2d single-cycle bipolar forward == binary XNOR-conv with threshold:
//   per tap popc(x&w) + popc(~x&~w) = 64 - popc(x^w); zero-padded tile makes
//   pad taps follow the same formula. pc = 576 - S + b_bit, S = sum popc(x^w).
//   out = (pc >= 577) = (S == 0 && b_bit) = (all 9 tap words EQUAL && b_bit).
//
// Single plain dispatch, no grid sync (R4: cg grid.sync ~80us on 8-XCD), no
// workspace. Each block handles (n, 2-row band) and is self-sufficient:
//   1a: pack 4-row x halo into LDS (coalesced HBM, 2x row redundancy)
//   1b: pack weights via BALLOT: lane l reads w[co][l][0..8] (wave reads one
//       contiguous 2304B slab -> fully coalesced), 9 ballots -> 9 words.
//       (R5 did stride-9 scattered reads here: ~400KB L2 traffic per block.)
//   2:  equality-conv for all 64 couts over the 2x56 band, float4 stores.

#define NB   16
#define CIN  64
#define HH   56
#define WWD  56
#define COUT 64
#define HW   (HH * WWD)             // 3136
#define RPB  2                      // output rows per block
#define BANDS (HH / RPB)            // 28
#define NBLOCKS (NB * BANDS)        // 448
#define XT_ROWS (RPB + 2)           // 4 padded input rows
#define XT_COLS 58                  // 56 + 2 pad cols
#define XT_WORDS (XT_ROWS * XT_COLS)  // 232

__global__ __launch_bounds__(256) void fused_conv(const float* __restrict__ x,
                                                  const float* __restrict__ w,
                                                  const float* __restrict__ bias,
                                                  float* __restrict__ out) {
    __shared__ uint64_t xt[XT_WORDS];     // 1856 B padded bit tile
    __shared__ uint64_t wsh[COUT * 9];    // 4608 B weight words
    __shared__ int bflag[COUT];

    int n    = blockIdx.x / BANDS;
    int band = blockIdx.x % BANDS;
    int h0   = band * RPB;

    // ---- phase 1a: pack x halo (rows h0-1 .. h0+RPB) into padded LDS tile
    if (threadIdx.x < XT_WORDS) {
        int t  = threadIdx.x;
        int rr = t / XT_COLS;
        int c  = t % XT_COLS;
        int gh = h0 - 1 + rr;
        uint64_t bits = 0;
        if (c >= 1 && c <= WWD && gh >= 0 && gh < HH) {
            const float* xp = x + (size_t)n * CIN * HW + (size_t)gh * WWD + (c - 1);
#pragma unroll
            for (int ch = 0; ch < CIN; ++ch)
                bits |= (uint64_t)(xp[(size_t)ch * HW] != 0.0f) << ch;
        }
        xt[t] = bits;
    }

    // ---- phase 1b: ballot weight pack; wave wid handles couts [16w,16w+16)
    {
        int wid  = threadIdx.x >> 6;
        int lane = threadIdx.x & 63;
#pragma unroll
        for (int i = 0; i < 16; ++i) {
            int co = wid * 16 + i;
            const float* wp = w + (size_t)co * (CIN * 9) + (size_t)lane * 9;
            float f0 = wp[0], f1 = wp[1], f2 = wp[2], f3 = wp[3], f4 = wp[4],
                  f5 = wp[5], f6 = wp[6], f7 = wp[7], f8 = wp[8];
            uint64_t b0 = __ballot(f0 > 0.0f), b1 = __ballot(f1 > 0.0f),
                     b2 = __ballot(f2 > 0.0f), b3 = __ballot(f3 > 0.0f),
                     b4 = __ballot(f4 > 0.0f), b5 = __ballot(f5 > 0.0f),
                     b6 = __ballot(f6 > 0.0f), b7 = __ballot(f7 > 0.0f),
                     b8 = __ballot(f8 > 0.0f);
            if (lane == 0) {
                uint64_t* d = &wsh[co * 9];
                d[0] = b0; d[1] = b1; d[2] = b2; d[3] = b3; d[4] = b4;
                d[5] = b5; d[6] = b6; d[7] = b7; d[8] = b8;
            }
        }
    }
    if (threadIdx.x < COUT) bflag[threadIdx.x] = bias[threadIdx.x] > 0.0f;
    __syncthreads();

    // ---- phase 2: equality-conv; 896 items of (2 rows x 4 cols) x 64 couts
    for (int item = threadIdx.x; item < COUT * 14; item += 256) {
        int co   = item / 14;
        int quad = item - co * 14;
        int c0   = quad * 4;

        uint64_t r[XT_ROWS][6];
#pragma unroll
        for (int rr = 0; rr < XT_ROWS; ++rr) {
            const ulonglong2* p = (const ulonglong2*)&xt[rr * XT_COLS + c0];  // 16B aligned
            ulonglong2 a = p[0], b = p[1], cc = p[2];
            r[rr][0] = a.x; r[rr][1] = a.y; r[rr][2] = b.x;
            r[rr][3] = b.y; r[rr][4] = cc.x; r[rr][5] = cc.y;
        }
        uint64_t wp[9];
#pragma unroll
        for (int k = 0; k < 9; ++k) wp[k] = wsh[co * 9 + k];
        int bb = bflag[co];

        float4 res[RPB];
#pragma unroll
        for (int orow = 0; orow < RPB; ++orow) {
            float v[4];
#pragma unroll
            for (int o = 0; o < 4; ++o) {
                int e = bb;
#pragma unroll
                for (int kh = 0; kh < 3; ++kh)
#pragma unroll
                    for (int kw = 0; kw < 3; ++kw)
                        e &= (r[orow + kh][o + kw] == wp[kh * 3 + kw]);
                v[o] = e ? 1.0f : 0.0f;
            }
            res[orow] = make_float4(v[0], v[1], v[2], v[3]);
        }
        float* ob = out + ((size_t)n * COUT + co) * HW + (size_t)h0 * WWD + c0;
        *(float4*)ob         = res[0];
        *(float4*)(ob + WWD) = res[1];
    }
}

extern "C" void kernel_launch(void* const* d_in, const int* in_sizes, int n_in,
                              void* d_out, int out_size, void* d_ws, size_t ws_size,
                              hipStream_t stream) {
    const float* x    = (const float*)d_in[0];
    const float* wgt  = (const float*)d_in[1];
    const float* bias = (const float*)d_in[2];
    float* out = (float*)d_out;

    fused_conv<<<NBLOCKS, 256, 0, stream>>>(x, wgt, bias, out);
}

// Round 7
// 17.319 us; speedup vs baseline: 5.2420x; 1.1663x over previous
//
#include <hip/hip_runtime.h>
#include <stdint.h>

// FSUConv2d single-cycle bipolar forward == binary XNOR-conv with threshold:
//   per tap popc(x&w) + popc(~x&~w) = 64 - popc(x^w); zero-padded tile makes
//   pad taps follow the same formula. pc = 576 - S + b_bit, S = sum popc(x^w).
//   out = (pc >= 577) = (S == 0 && b_bit) = (all 9 tap words EQUAL && b_bit).
//
// Single plain dispatch (R4: grid.sync ~80us; R2->R3: ~4us per dispatch).
// Block = (n, 2-row band), 512 threads, self-sufficient:
//   1a: pack 4-row x halo into LDS tile; task = (row, 8-ch group, 4-px group):
//       8 float4 loads per thread (R6 used a 64-deep scalar chain on 232
//       threads -> latency-bound; this is 4x fewer load instrs, 2x threads).
//   1b: ballot weight pack (wave reads contiguous 2304B slab per cout).
//   2:  equality-conv, all 64 couts x 2x56 band, float4 stores.

#define NB   16
#define CIN  64
#define HH   56
#define WWD  56
#define COUT 64
#define HW   (HH * WWD)             // 3136
#define RPB  2                      // output rows per block
#define BANDS (HH / RPB)            // 28
#define NBLOCKS (NB * BANDS)        // 448
#define XT_ROWS (RPB + 2)           // 4 padded input rows
#define XT_COLS 58                  // 56 + 2 pad cols
#define XT_WORDS (XT_ROWS * XT_COLS)  // 232

__global__ __launch_bounds__(512) void fused_conv(const float* __restrict__ x,
                                                  const float* __restrict__ w,
                                                  const float* __restrict__ bias,
                                                  float* __restrict__ out) {
    __shared__ uint64_t xt[XT_WORDS];     // 1856 B padded bit tile
    __shared__ uint64_t wsh[COUT * 9];    // 4608 B weight words
    __shared__ int bflag[COUT];

    int n    = blockIdx.x / BANDS;
    int band = blockIdx.x % BANDS;
    int h0   = band * RPB;

    // ---- phase 1a: pack x halo. 448 tasks = 4 rows x 8 ch-groups x 14 px-quads
    {
        int t = threadIdx.x;
        if (t < 448) {
            int row = t / 112;            // 0..3  (gh = h0-1+row)
            int rem = t - row * 112;
            int cg8 = rem / 14;           // 0..7  channels [8*cg8, 8*cg8+8)
            int pg  = rem - cg8 * 14;     // 0..13 pixel cols [4*pg, 4*pg+4)
            int gh  = h0 - 1 + row;
            int pc0 = pg * 4;
            uint32_t b0 = 0, b1 = 0, b2 = 0, b3 = 0;
            if (gh >= 0 && gh < HH) {
                const float* xp = x + (size_t)n * CIN * HW + (size_t)(cg8 * 8) * HW
                                    + (size_t)gh * WWD + pc0;
#pragma unroll
                for (int i = 0; i < 8; ++i) {
                    float4 v = *(const float4*)(xp + (size_t)i * HW);
                    b0 |= (uint32_t)(v.x != 0.0f) << i;
                    b1 |= (uint32_t)(v.y != 0.0f) << i;
                    b2 |= (uint32_t)(v.z != 0.0f) << i;
                    b3 |= (uint32_t)(v.w != 0.0f) << i;
                }
            }
            uint8_t* xb = (uint8_t*)xt;
            int base = (row * XT_COLS + 1 + pc0) * 8 + cg8;
            xb[base]      = (uint8_t)b0;
            xb[base + 8]  = (uint8_t)b1;
            xb[base + 16] = (uint8_t)b2;
            xb[base + 24] = (uint8_t)b3;
        } else if (t < 456) {
            int i = t - 448;              // zero the 8 pad-column words
            int row = i >> 1, col = (i & 1) ? (XT_COLS - 1) : 0;
            xt[row * XT_COLS + col] = 0ull;
        }
    }

    // ---- phase 1b: ballot weight pack; wave wid -> couts [8*wid, 8*wid+8)
    {
        int wid  = threadIdx.x >> 6;
        int lane = threadIdx.x & 63;
#pragma unroll
        for (int i = 0; i < 8; ++i) {
            int co = wid * 8 + i;
            const float* wp = w + (size_t)co * (CIN * 9) + (size_t)lane * 9;
            float f0 = wp[0], f1 = wp[1], f2 = wp[2], f3 = wp[3], f4 = wp[4],
                  f5 = wp[5], f6 = wp[6], f7 = wp[7], f8 = wp[8];
            uint64_t q0 = __ballot(f0 > 0.0f), q1 = __ballot(f1 > 0.0f),
                     q2 = __ballot(f2 > 0.0f), q3 = __ballot(f3 > 0.0f),
                     q4 = __ballot(f4 > 0.0f), q5 = __ballot(f5 > 0.0f),
                     q6 = __ballot(f6 > 0.0f), q7 = __ballot(f7 > 0.0f),
                     q8 = __ballot(f8 > 0.0f);
            if (lane == 0) {
                uint64_t* d = &wsh[co * 9];
                d[0] = q0; d[1] = q1; d[2] = q2; d[3] = q3; d[4] = q4;
                d[5] = q5; d[6] = q6; d[7] = q7; d[8] = q8;
            }
        }
    }
    if (threadIdx.x < COUT) bflag[threadIdx.x] = bias[threadIdx.x] > 0.0f;
    __syncthreads();

    // ---- phase 2: equality-conv; 896 items of (2 rows x 4 cols) x 64 couts
#pragma unroll
    for (int it = 0; it < 2; ++it) {
        int item = threadIdx.x + it * 512;
        if (item >= COUT * 14) break;
        int co   = item / 14;
        int quad = item - co * 14;
        int c0   = quad * 4;

        uint64_t r[XT_ROWS][6];
#pragma unroll
        for (int rr = 0; rr < XT_ROWS; ++rr) {
            const ulonglong2* p = (const ulonglong2*)&xt[rr * XT_COLS + c0];  // 16B aligned
            ulonglong2 a = p[0], b = p[1], cc = p[2];
            r[rr][0] = a.x; r[rr][1] = a.y; r[rr][2] = b.x;
            r[rr][3] = b.y; r[rr][4] = cc.x; r[rr][5] = cc.y;
        }
        uint64_t wp[9];
#pragma unroll
        for (int k = 0; k < 9; ++k) wp[k] = wsh[co * 9 + k];
        int bb = bflag[co];

        float4 res[RPB];
#pragma unroll
        for (int orow = 0; orow < RPB; ++orow) {
            float v[4];
#pragma unroll
            for (int o = 0; o < 4; ++o) {
                int e = bb;
#pragma unroll
                for (int kh = 0; kh < 3; ++kh)
#pragma unroll
                    for (int kw = 0; kw < 3; ++kw)
                        e &= (r[orow + kh][o + kw] == wp[kh * 3 + kw]);
                v[o] = e ? 1.0f : 0.0f;
            }
            res[orow] = make_float4(v[0], v[1], v[2], v[3]);
        }
        float* ob = out + ((size_t)n * COUT + co) * HW + (size_t)h0 * WWD + c0;
        *(float4*)ob         = res[0];
        *(float4*)(ob + WWD) = res[1];
    }
}

extern "C" void kernel_launch(void* const* d_in, const int* in_sizes, int n_in,
                              void* d_out, int out_size, void* d_ws, size_t ws_size,
                              hipStream_t stream) {
    const float* x    = (const float*)d_in[0];
    const float* wgt  = (const float*)d_in[1];
    const float* bias = (const float*)d_in[2];
    float* out = (float*)d_out;

    fused_conv<<<NBLOCKS, 512, 0, stream>>>(x, wgt, bias, out);
}

// Round 8
// 14.879 us; speedup vs baseline: 6.1017x; 1.1640x over previous
//
#include <hip/hip_runtime.h>
#include <stdint.h>

// FSUConv2d single-cycle bipolar forward == binary XNOR-conv with threshold:
//   per tap popc(x&w) + popc(~x&~w) = 64 - popc(x^w); zero-padded tile makes
//   pad taps follow the same formula. pc = 576 - S + b_bit, S = sum popc(x^w).
//   out = (pc >= 577) = (S == 0 && b_bit) = (all 9 tap words EQUAL && b_bit).
//
// Single plain dispatch (R4: grid.sync ~80us). Block = (n, 4-row band),
// 512 threads, self-sufficient. 224 blocks <= 256 CUs -> ONE scheduling
// round (R7's 448 blocks took 2 rounds); halo redundancy 1.5x (was 2x).
//   1a: pack 6-row x halo into LDS; task = (row, 8-ch group, 4-px group),
//       8 float4 loads per task, fully coalesced.
//   1b: ballot weight pack (wave reads contiguous 2304B slab per cout).
//   2:  equality-conv, 64 couts x (4 rows x 4 cols) items, float4 stores.

#define NB   16
#define CIN  64
#define HH   56
#define WWD  56
#define COUT 64
#define HW   (HH * WWD)             // 3136
#define RPB  4                      // output rows per block
#define BANDS (HH / RPB)            // 14
#define NBLOCKS (NB * BANDS)        // 224
#define XT_ROWS (RPB + 2)           // 6 padded input rows
#define XT_COLS 58                  // 56 + 2 pad cols
#define XT_WORDS (XT_ROWS * XT_COLS)  // 348
#define NPTASK (XT_ROWS * 8 * 14)   // 672 pack tasks
#define NPADW  (XT_ROWS * 2)        // 12 pad-column words

__global__ __launch_bounds__(512) void fused_conv(const float* __restrict__ x,
                                                  const float* __restrict__ w,
                                                  const float* __restrict__ bias,
                                                  float* __restrict__ out) {
    __shared__ uint64_t xt[XT_WORDS];     // 2784 B padded bit tile
    __shared__ uint64_t wsh[COUT * 9];    // 4608 B weight words
    __shared__ int bflag[COUT];

    int n    = blockIdx.x / BANDS;
    int band = blockIdx.x % BANDS;
    int h0   = band * RPB;

    // ---- phase 1a: pack x halo rows h0-1 .. h0+RPB into padded LDS tile
    for (int t = threadIdx.x; t < NPTASK + NPADW; t += 512) {
        if (t < NPTASK) {
            int row = t / 112;            // 0..5   (gh = h0-1+row)
            int rem = t - row * 112;
            int cg8 = rem / 14;           // 0..7   channels [8*cg8, 8*cg8+8)
            int pg  = rem - cg8 * 14;     // 0..13  pixel cols [4*pg, 4*pg+4)
            int gh  = h0 - 1 + row;
            int pc0 = pg * 4;
            uint32_t b0 = 0, b1 = 0, b2 = 0, b3 = 0;
            if (gh >= 0 && gh < HH) {
                const float* xp = x + (size_t)n * CIN * HW + (size_t)(cg8 * 8) * HW
                                    + (size_t)gh * WWD + pc0;
#pragma unroll
                for (int i = 0; i < 8; ++i) {
                    float4 v = *(const float4*)(xp + (size_t)i * HW);
                    b0 |= (uint32_t)(v.x != 0.0f) << i;
                    b1 |= (uint32_t)(v.y != 0.0f) << i;
                    b2 |= (uint32_t)(v.z != 0.0f) << i;
                    b3 |= (uint32_t)(v.w != 0.0f) << i;
                }
            }
            uint8_t* xb = (uint8_t*)xt;
            int base = (row * XT_COLS + 1 + pc0) * 8 + cg8;
            xb[base]      = (uint8_t)b0;
            xb[base + 8]  = (uint8_t)b1;
            xb[base + 16] = (uint8_t)b2;
            xb[base + 24] = (uint8_t)b3;
        } else {
            int i = t - NPTASK;           // zero the pad-column words
            int row = i >> 1, col = (i & 1) ? (XT_COLS - 1) : 0;
            xt[row * XT_COLS + col] = 0ull;
        }
    }

    // ---- phase 1b: ballot weight pack; wave wid -> couts [8*wid, 8*wid+8)
    {
        int wid  = threadIdx.x >> 6;
        int lane = threadIdx.x & 63;
#pragma unroll
        for (int i = 0; i < 8; ++i) {
            int co = wid * 8 + i;
            const float* wp = w + (size_t)co * (CIN * 9) + (size_t)lane * 9;
            float f0 = wp[0], f1 = wp[1], f2 = wp[2], f3 = wp[3], f4 = wp[4],
                  f5 = wp[5], f6 = wp[6], f7 = wp[7], f8 = wp[8];
            uint64_t q0 = __ballot(f0 > 0.0f), q1 = __ballot(f1 > 0.0f),
                     q2 = __ballot(f2 > 0.0f), q3 = __ballot(f3 > 0.0f),
                     q4 = __ballot(f4 > 0.0f), q5 = __ballot(f5 > 0.0f),
                     q6 = __ballot(f6 > 0.0f), q7 = __ballot(f7 > 0.0f),
                     q8 = __ballot(f8 > 0.0f);
            if (lane == 0) {
                uint64_t* d = &wsh[co * 9];
                d[0] = q0; d[1] = q1; d[2] = q2; d[3] = q3; d[4] = q4;
                d[5] = q5; d[6] = q6; d[7] = q7; d[8] = q8;
            }
        }
    }
    if (threadIdx.x < COUT) bflag[threadIdx.x] = bias[threadIdx.x] > 0.0f;
    __syncthreads();

    // ---- phase 2: equality-conv; 896 items of (4 rows x 4 cols) x 64 couts
    for (int item = threadIdx.x; item < COUT * 14; item += 512) {
        int co   = item / 14;
        int quad = item - co * 14;
        int c0   = quad * 4;

        uint64_t r[XT_ROWS][6];
#pragma unroll
        for (int rr = 0; rr < XT_ROWS; ++rr) {
            const ulonglong2* p = (const ulonglong2*)&xt[rr * XT_COLS + c0];  // 16B aligned
            ulonglong2 a = p[0], b = p[1], cc = p[2];
            r[rr][0] = a.x; r[rr][1] = a.y; r[rr][2] = b.x;
            r[rr][3] = b.y; r[rr][4] = cc.x; r[rr][5] = cc.y;
        }
        uint64_t wp[9];
#pragma unroll
        for (int k = 0; k < 9; ++k) wp[k] = wsh[co * 9 + k];
        int bb = bflag[co];

        float* ob = out + ((size_t)n * COUT + co) * HW + (size_t)h0 * WWD + c0;
#pragma unroll
        for (int orow = 0; orow < RPB; ++orow) {
            float v[4];
#pragma unroll
            for (int o = 0; o < 4; ++o) {
                int e = bb;
#pragma unroll
                for (int kh = 0; kh < 3; ++kh)
#pragma unroll
                    for (int kw = 0; kw < 3; ++kw)
                        e &= (r[orow + kh][o + kw] == wp[kh * 3 + kw]);
                v[o] = e ? 1.0f : 0.0f;
            }
            *(float4*)(ob + (size_t)orow * WWD) = make_float4(v[0], v[1], v[2], v[3]);
        }
    }
}

extern "C" void kernel_launch(void* const* d_in, const int* in_sizes, int n_in,
                              void* d_out, int out_size, void* d_ws, size_t ws_size,
                              hipStream_t stream) {
    const float* x    = (const float*)d_in[0];
    const float* wgt  = (const float*)d_in[1];
    const float* bias = (const float*)d_in[2];
    float* out = (float*)d_out;

    fused_conv<<<NBLOCKS, 512, 0, stream>>>(x, wgt, bias, out);
}

// Round 9
// 13.373 us; speedup vs baseline: 6.7886x; 1.1126x over previous
//
#include <hip/hip_runtime.h>
#include <stdint.h>

// FSUConv2d single-cycle bipolar forward == binary XNOR-conv with threshold:
//   per tap popc(x&w) + popc(~x&~w) = 64 - popc(x^w); zero-padded tile makes
//   pad taps follow the same formula. pc = 576 - S + b_bit, S = sum popc(x^w).
//   out = (pc >= 577) = (S == 0 && b_bit) = (all 9 tap words EQUAL && b_bit).
//
// Single plain dispatch (R4: grid.sync ~80us). Block = (n, 4-row band),
// 512 threads, 224 blocks (one scheduling round on 256 CUs).
//   1a: pack 6-row x halo into LDS (coalesced float4 loads).
//   1b: ballot weight pack (wave reads contiguous 2304B slab per cout).
//   2:  CENTER-TAP REJECTION: an output is 1 only if all 9 tap words match
//       exactly; the center tap alone rejects with P(pass)=2^-64 per word.
//       Fast path: 12 b128 LDS reads + 32 cmps + zero stores. Full 9-tap
//       evaluation (halo rows 0/5 + 9 wp words) only in the cold branch --
//       exact for any input, wave-uniform skip for real bitstream data.

#define NB   16
#define CIN  64
#define HH   56
#define WWD  56
#define COUT 64
#define HW   (HH * WWD)             // 3136
#define RPB  4                      // output rows per block
#define BANDS (HH / RPB)            // 14
#define NBLOCKS (NB * BANDS)        // 224
#define XT_ROWS (RPB + 2)           // 6 padded input rows
#define XT_COLS 58                  // 56 + 2 pad cols
#define XT_WORDS (XT_ROWS * XT_COLS)  // 348
#define NPTASK (XT_ROWS * 8 * 14)   // 672 pack tasks
#define NPADW  (XT_ROWS * 2)        // 12 pad-column words

__global__ __launch_bounds__(512) void fused_conv(const float* __restrict__ x,
                                                  const float* __restrict__ w,
                                                  const float* __restrict__ bias,
                                                  float* __restrict__ out) {
    __shared__ uint64_t xt[XT_WORDS];     // 2784 B padded bit tile
    __shared__ uint64_t wsh[COUT * 9];    // 4608 B weight words
    __shared__ int bflag[COUT];

    int n    = blockIdx.x / BANDS;
    int band = blockIdx.x % BANDS;
    int h0   = band * RPB;

    // ---- phase 1a: pack x halo rows h0-1 .. h0+RPB into padded LDS tile
    for (int t = threadIdx.x; t < NPTASK + NPADW; t += 512) {
        if (t < NPTASK) {
            int row = t / 112;            // 0..5   (gh = h0-1+row)
            int rem = t - row * 112;
            int cg8 = rem / 14;           // 0..7   channels [8*cg8, 8*cg8+8)
            int pg  = rem - cg8 * 14;     // 0..13  pixel cols [4*pg, 4*pg+4)
            int gh  = h0 - 1 + row;
            int pc0 = pg * 4;
            uint32_t b0 = 0, b1 = 0, b2 = 0, b3 = 0;
            if (gh >= 0 && gh < HH) {
                const float* xp = x + (size_t)n * CIN * HW + (size_t)(cg8 * 8) * HW
                                    + (size_t)gh * WWD + pc0;
#pragma unroll
                for (int i = 0; i < 8; ++i) {
                    float4 v = *(const float4*)(xp + (size_t)i * HW);
                    b0 |= (uint32_t)(v.x != 0.0f) << i;
                    b1 |= (uint32_t)(v.y != 0.0f) << i;
                    b2 |= (uint32_t)(v.z != 0.0f) << i;
                    b3 |= (uint32_t)(v.w != 0.0f) << i;
                }
            }
            uint8_t* xb = (uint8_t*)xt;
            int base = (row * XT_COLS + 1 + pc0) * 8 + cg8;
            xb[base]      = (uint8_t)b0;
            xb[base + 8]  = (uint8_t)b1;
            xb[base + 16] = (uint8_t)b2;
            xb[base + 24] = (uint8_t)b3;
        } else {
            int i = t - NPTASK;           // zero the pad-column words
            int row = i >> 1, col = (i & 1) ? (XT_COLS - 1) : 0;
            xt[row * XT_COLS + col] = 0ull;
        }
    }

    // ---- phase 1b: ballot weight pack; wave wid -> couts [8*wid, 8*wid+8)
    {
        int wid  = threadIdx.x >> 6;
        int lane = threadIdx.x & 63;
#pragma unroll
        for (int i = 0; i < 8; ++i) {
            int co = wid * 8 + i;
            const float* wp = w + (size_t)co * (CIN * 9) + (size_t)lane * 9;
            float f0 = wp[0], f1 = wp[1], f2 = wp[2], f3 = wp[3], f4 = wp[4],
                  f5 = wp[5], f6 = wp[6], f7 = wp[7], f8 = wp[8];
            uint64_t q0 = __ballot(f0 > 0.0f), q1 = __ballot(f1 > 0.0f),
                     q2 = __ballot(f2 > 0.0f), q3 = __ballot(f3 > 0.0f),
                     q4 = __ballot(f4 > 0.0f), q5 = __ballot(f5 > 0.0f),
                     q6 = __ballot(f6 > 0.0f), q7 = __ballot(f7 > 0.0f),
                     q8 = __ballot(f8 > 0.0f);
            if (lane == 0) {
                uint64_t* d = &wsh[co * 9];
                d[0] = q0; d[1] = q1; d[2] = q2; d[3] = q3; d[4] = q4;
                d[5] = q5; d[6] = q6; d[7] = q7; d[8] = q8;
            }
        }
    }
    if (threadIdx.x < COUT) bflag[threadIdx.x] = bias[threadIdx.x] > 0.0f;
    __syncthreads();

    // ---- phase 2: center-tap rejection conv. 448 threads = 14 quads x 32
    //      cout-pairs; each thread: 2 couts x 4 rows x 4 cols.
    int t = threadIdx.x;
    if (t >= 448) return;
    int q   = t % 14;
    int cp  = t / 14;                 // cout pair index
    int c0  = q * 4;
    int co0 = cp * 2;

    // center rows 1..4, cols c0..c0+5 (16B-aligned: 58*rr+c0 is even)
    uint64_t rc[4][6];
#pragma unroll
    for (int rr = 0; rr < 4; ++rr) {
        const ulonglong2* p = (const ulonglong2*)&xt[(rr + 1) * XT_COLS + c0];
        ulonglong2 a = p[0], b = p[1], cc = p[2];
        rc[rr][0] = a.x; rc[rr][1] = a.y; rc[rr][2] = b.x;
        rc[rr][3] = b.y; rc[rr][4] = cc.x; rc[rr][5] = cc.y;
    }
    uint64_t wc0 = wsh[co0 * 9 + 4];
    uint64_t wc1 = wsh[(co0 + 1) * 9 + 4];
    int bb0 = bflag[co0], bb1 = bflag[co0 + 1];

    int hit0 = 0, hit1 = 0;
#pragma unroll
    for (int orow = 0; orow < 4; ++orow)
#pragma unroll
        for (int o = 0; o < 4; ++o) {
            uint64_t cw = rc[orow][o + 1];   // center tap for (orow, o)
            hit0 |= (cw == wc0);
            hit1 |= (cw == wc1);
        }

    float* ob0 = out + ((size_t)n * COUT + co0) * HW + (size_t)h0 * WWD + c0;
    float* ob1 = ob0 + HW;

    if (!((hit0 & bb0) | (hit1 & bb1))) {
        // fast path: every output provably 0 (center tap mismatch everywhere)
        float4 z = make_float4(0.0f, 0.0f, 0.0f, 0.0f);
#pragma unroll
        for (int orow = 0; orow < 4; ++orow) {
            *(float4*)(ob0 + (size_t)orow * WWD) = z;
            *(float4*)(ob1 + (size_t)orow * WWD) = z;
        }
        return;
    }

    // ---- cold full path: load halo rows 0,5 and evaluate all 9 taps exactly
    uint64_t rA[6][6];
#pragma unroll
    for (int c = 0; c < 6; ++c) {
        rA[0][c] = xt[0 * XT_COLS + c0 + c];
        rA[5][c] = xt[5 * XT_COLS + c0 + c];
    }
#pragma unroll
    for (int rr = 0; rr < 4; ++rr)
#pragma unroll
        for (int c = 0; c < 6; ++c) rA[rr + 1][c] = rc[rr][c];

#pragma unroll
    for (int ci = 0; ci < 2; ++ci) {
        int co = co0 + ci;
        int bb = ci ? bb1 : bb0;
        float* ob = ci ? ob1 : ob0;
        uint64_t wp[9];
#pragma unroll
        for (int k = 0; k < 9; ++k) wp[k] = wsh[co * 9 + k];
#pragma unroll
        for (int orow = 0; orow < 4; ++orow) {
            float v[4];
#pragma unroll
            for (int o = 0; o < 4; ++o) {
                int e = bb;
#pragma unroll
                for (int kh = 0; kh < 3; ++kh)
#pragma unroll
                    for (int kw = 0; kw < 3; ++kw)
                        e &= (rA[orow + kh][o + kw] == wp[kh * 3 + kw]);
                v[o] = e ? 1.0f : 0.0f;
            }
            *(float4*)(ob + (size_t)orow * WWD) = make_float4(v[0], v[1], v[2], v[3]);
        }
    }
}

extern "C" void kernel_launch(void* const* d_in, const int* in_sizes, int n_in,
                              void* d_out, int out_size, void* d_ws, size_t ws_size,
                              hipStream_t stream) {
    const float* x    = (const float*)d_in[0];
    const float* wgt  = (const float*)d_in[1];
    const float* bias = (const float*)d_in[2];
    float* out = (float*)d_out;

    fused_conv<<<NBLOCKS, 512, 0, stream>>>(x, wgt, bias, out);
}